// Round 1
// baseline (177.238 us; speedup 1.0000x reference)
//
#include <hip/hip_runtime.h>
#include <stdint.h>
#include <stddef.h>

// ============================================================================
// SumSampler: bit-exact replication of the JAX reference sampler.
//
// GAMBLES (documented for iteration):
//   G1: JAX partitionable threefry (default since ~0.4.30):
//       split -> foldlike: key'=enc(0,0), sub=enc(0,1);
//       random_bits[n] = o0 ^ o1 of enc_sub(hi=0, lo=n), n = row-major index.
//   G2: f32 log = Eigen/Cephes plog, FMA at pmadd sites, UNFUSED tail
//       (Variant-E). Alternatives: Variant-X (greedy contraction),
//       Variant-N (no FMA at all).
//   G3: d_out dtype = float32 for all three concatenated outputs.
// ============================================================================

namespace {

constexpr int B = 512, S = 2048, D = 4, NC = 10;
constexpr int BS = B * S;                  // 1048576
constexpr size_t OUT1_OFF = (size_t)BS * D;   // 4194304
constexpr size_t OUT2_OFF = (size_t)BS * D * 2; // 8388608

// ---------------- constexpr Threefry2x32 (for compile-time key derivation) --
constexpr uint32_t crotl(uint32_t x, int d) { return (x << d) | (x >> (32 - d)); }
struct CU2 { uint32_t a, b; };
constexpr CU2 ctf(uint32_t k0, uint32_t k1, uint32_t c0, uint32_t c1) {
  uint32_t ks2 = k0 ^ k1 ^ 0x1BD11BDAu;
  uint32_t x0 = c0 + k0, x1 = c1 + k1;
  const int rots[8] = {13, 15, 26, 6, 17, 29, 16, 24};
  const uint32_t ks[3] = {k0, k1, ks2};
  for (int blk = 0; blk < 5; ++blk) {
    for (int j = 0; j < 4; ++j) {
      int r = rots[(blk & 1) * 4 + j];
      x0 += x1; x1 = crotl(x1, r); x1 ^= x0;
    }
    x0 += ks[(blk + 1) % 3];
    x1 += ks[(blk + 2) % 3] + (uint32_t)(blk + 1);
  }
  return CU2{x0, x1};
}

struct Keys { uint32_t kx[D]; uint32_t ky[D]; };
constexpr Keys make_keys() {
  Keys K{};
  uint32_t a = 0u, b = 42u;  // jax.random.key(42) -> (0, 42)
  for (int i = 0; i < D; ++i) {
    CU2 sub = ctf(a, b, 0u, 1u);  // split[1] = sub  (foldlike)
    CU2 nk  = ctf(a, b, 0u, 0u);  // split[0] = carried key
    K.kx[i] = sub.a; K.ky[i] = sub.b;
    a = nk.a; b = nk.b;
  }
  return K;
}
constexpr Keys KEYS = make_keys();

// ---------------- device Threefry2x32 ---------------------------------------
struct U2 { uint32_t a, b; };
__device__ __forceinline__ uint32_t rotl32(uint32_t x, int d) {
  return (x << d) | (x >> (32 - d));
}
__device__ __forceinline__ U2 tf(uint32_t k0, uint32_t k1, uint32_t c0, uint32_t c1) {
  uint32_t ks2 = k0 ^ k1 ^ 0x1BD11BDAu;
  uint32_t x0 = c0 + k0, x1 = c1 + k1;
#define TF_RND(r) { x0 += x1; x1 = rotl32(x1, (r)); x1 ^= x0; }
  TF_RND(13) TF_RND(15) TF_RND(26) TF_RND(6)   x0 += k1;  x1 += ks2 + 1u;
  TF_RND(17) TF_RND(29) TF_RND(16) TF_RND(24)  x0 += ks2; x1 += k0 + 2u;
  TF_RND(13) TF_RND(15) TF_RND(26) TF_RND(6)   x0 += k0;  x1 += k1 + 3u;
  TF_RND(17) TF_RND(29) TF_RND(16) TF_RND(24)  x0 += k1;  x1 += ks2 + 4u;
  TF_RND(13) TF_RND(15) TF_RND(26) TF_RND(6)   x0 += ks2; x1 += k0 + 5u;
#undef TF_RND
  return U2{x0, x1};
}

// ---------------- f32 log: Eigen/Cephes plog, Variant-E ---------------------
// FMA (__fmaf_rn) at the pmadd sites, unfused IEEE ops elsewhere. Inputs here
// are always positive, finite, normal — no special-case handling needed.
__device__ __forceinline__ float xla_logf(float a) {
  uint32_t bits = __float_as_uint(a);
  float e = (float)((int)(bits >> 23) - 126);               // pfrexp exponent
  float m = __uint_as_float((bits & 0x007fffffu) | 0x3f000000u); // [0.5, 1)
  bool mlt = m < 0.707106781186547524f;                     // SQRTHF
  float tmp = mlt ? m : 0.0f;
  float x = __fsub_rn(m, 1.0f);
  e = __fsub_rn(e, mlt ? 1.0f : 0.0f);
  x = __fadd_rn(x, tmp);
  float x2 = __fmul_rn(x, x);
  float x3 = __fmul_rn(x2, x);
  float y  = __fmaf_rn(7.0376836292e-2f,  x, -1.1514610310e-1f);
  float y1 = __fmaf_rn(-1.2420140846e-1f, x,  1.4249322787e-1f);
  float y2 = __fmaf_rn(2.0000714765e-1f,  x, -2.4999993993e-1f);
  y  = __fmaf_rn(y,  x,  1.1676998740e-1f);
  y1 = __fmaf_rn(y1, x, -1.6668057665e-1f);
  y2 = __fmaf_rn(y2, x,  3.3333331174e-1f);
  y  = __fmaf_rn(y, x3, y1);
  y  = __fmaf_rn(y, x3, y2);
  y  = __fmul_rn(y, x3);                 // (A) unfused tail begins
  y1 = __fmul_rn(e, -2.12194440e-4f);    // (B)
  tmp = __fmul_rn(x2, 0.5f);             // (C)
  y = __fadd_rn(y, y1);                  // (D)
  x = __fsub_rn(x, tmp);                 // (E)
  y2 = __fmul_rn(e, 0.693359375f);       // (F)
  x = __fadd_rn(x, y);                   // (G)
  x = __fadd_rn(x, y2);                  // (H)
  return x;
}

// uniform(minval=tiny, maxval=1) -> gumbel, bit-faithful to jax._src.random
__device__ __forceinline__ float gumbel_from_bits(uint32_t bits) {
  float f = __fsub_rn(__uint_as_float((bits >> 9) | 0x3f800000u), 1.0f);
  float u = __fadd_rn(f, 1.17549435e-38f);  // == f unless f == 0 -> tiny
  float l1 = xla_logf(u);                   // log(u) in [-87.34, -1.2e-7]
  float l2 = xla_logf(-l1);
  return -l2;
}

// ---------------- main sampling kernel --------------------------------------
__global__ __launch_bounds__(256) void sample_kernel(
    const float* __restrict__ logits,   // [B, D, NC]
    const float* __restrict__ counters, // [D, NC]
    const int*   __restrict__ s_in,     // [B]
    float* __restrict__ out)            // concat(n1_samples, n2d, weights)
{
  __shared__ float s_alog[D * NC];      // 0.1f * log(counters)
  int t = threadIdx.x;
  if (t < D * NC) s_alog[t] = __fmul_rn(0.1f, xla_logf(counters[t]));
  __syncthreads();

  int tid = blockIdx.x * 256 + t;       // 0 .. BS-1, grid sized exactly
  int b = tid >> 11;                    // / S
  int sval = s_in[b];
  int mx0 = sval / 1000;
  int mx1 = (sval / 100) % 10;
  int mx2 = (sval / 10) % 10;
  int mx3 = sval % 10;
  int mx[D] = {mx0, mx1, mx2, mx3};

  uint32_t n0 = (uint32_t)tid * (uint32_t)NC;  // row-major gumbel index base
  int con = 0;
  int dg[D];
  for (int i = 0; i < D; ++i) {
    uint32_t kx = KEYS.kx[i], ky = KEYS.ky[i];
    int mxi = mx[i];
    float best = -__builtin_inff();
    int bi = 0;
#pragma unroll
    for (int c = 0; c < NC; ++c) {
      U2 r = tf(kx, ky, 0u, n0 + (uint32_t)c);
      float g = gumbel_from_bits(r.a ^ r.b);           // bits1 ^ bits2
      float p = __fsub_rn(logits[(b * D + i) * NC + c], s_alog[i * NC + c]);
      float v = __fadd_rn(g, p);
      bool allowed = (con != 0) || (c <= mxi);         // minim is always 0
      if (allowed && v > best) { best = v; bi = c; }   // first max wins
    }
    dg[i] = bi;
    con |= (bi != mxi);    // constraint = max(samp != maxim, constraint)
  }

  int n1v = dg[0] * 1000 + dg[1] * 100 + dg[2] * 10 + dg[3];
  int n2 = sval - n1v;     // guaranteed in [0, 10^D)
  // reference's quotient-sort decimalisation == plain digits of n2
  int q0 = n2 / 1000, q1 = (n2 / 100) % 10, q2 = (n2 / 10) % 10, q3 = n2 % 10;

  size_t o = (size_t)tid * D;
  out[o + 0] = (float)dg[0];
  out[o + 1] = (float)dg[1];
  out[o + 2] = (float)dg[2];
  out[o + 3] = (float)dg[3];
  out[OUT1_OFF + o + 0] = (float)q0;
  out[OUT1_OFF + o + 1] = (float)q1;
  out[OUT1_OFF + o + 2] = (float)q2;
  out[OUT1_OFF + o + 3] = (float)q3;
}

// ---------------- per-row multiplicity (weights) ----------------------------
__global__ __launch_bounds__(1024) void weights_kernel(float* __restrict__ out) {
  __shared__ int hist[10000];           // 40 KB LDS
  int b = blockIdx.x;
  for (int i = threadIdx.x; i < 10000; i += 1024) hist[i] = 0;
  __syncthreads();
  int vals[2];
#pragma unroll
  for (int k = 0; k < 2; ++k) {
    int sidx = (int)threadIdx.x + k * 1024;
    const float* p = out + ((size_t)(b * S + sidx)) * D;
    int v = 1000 * (int)p[0] + 100 * (int)p[1] + 10 * (int)p[2] + (int)p[3];
    vals[k] = v;
    atomicAdd(&hist[v], 1);
  }
  __syncthreads();
#pragma unroll
  for (int k = 0; k < 2; ++k) {
    int sidx = (int)threadIdx.x + k * 1024;
    out[OUT2_OFF + (size_t)b * S + sidx] = (float)hist[vals[k]];
  }
}

}  // namespace

extern "C" void kernel_launch(void* const* d_in, const int* in_sizes, int n_in,
                              void* d_out, int out_size, void* d_ws, size_t ws_size,
                              hipStream_t stream) {
  const float* logits   = (const float*)d_in[0];  // [512,4,10]
  const float* counters = (const float*)d_in[1];  // [4,10]
  const int*   s_in     = (const int*)d_in[2];    // [512]
  float* out = (float*)d_out;

  sample_kernel<<<BS / 256, 256, 0, stream>>>(logits, counters, s_in, out);
  weights_kernel<<<B, 1024, 0, stream>>>(out);
}